// Round 20
// baseline (347.381 us; speedup 1.0000x reference)
//
#include <hip/hip_runtime.h>
#include <hip/hip_fp16.h>
#include <math.h>

#define BATCH 128
#define NTOK  343
#define NPAD  352
#define CDIM  384
#define NH    12
#define DH    32
#define NWIN  32
#define MTOK  (BATCH*NTOK)   // 43904
#define NN    (NTOK*NTOK)    // 117649
#define QKVF  (3*CDIM)       // 1152
#define KSTR  40             // attn K LDS row stride (halves)
#define VSTR  360
#define PSTR  106            // chunked P buffer stride (halves); conflict-verified
#define MBW   11             // u32 words per packed mask row
#define BTI   22             // bias_sw i-tiles
#define BJT   22             // bias_sw j-tiles
#define BSWT  (BTI*BJT*256)  // elements per head in bias_sw (123904)

typedef float    f32x4 __attribute__((ext_vector_type(4)));
typedef _Float16 half8 __attribute__((ext_vector_type(8)));
typedef _Float16 half4 __attribute__((ext_vector_type(4)));

#define LDS_K   (NPAD*KSTR)                 // 14080 halves = 28160 B
#define LDS_V   (DH*VSTR)                   // 11520 halves = 23040 B
#define LDS_P   (16*PSTR)                   // 1696 halves  = 3392 B per wave
#define LDS_TOT (LDS_K + LDS_V + 8*LDS_P)   // 39168 halves = 78336 B

// prep_k grid sections (x-conversion REMOVED -- fused into QKV GEMM staging)
#define NWQ   (QKVF*CDIM)          // 442,368
#define NWP   (CDIM*CDIM)          // 147,456
#define NWQB  (NWQ/2048)           // 216
#define NWPB  (NWP/2048)           // 72
#define NMKB  ((NWIN*NTOK+3)/4)    // 2744
#define NBSB  ((BSWT+255)/256)     // 484
#define PREPB (NWQB+NWPB+NMKB+NBSB)  // 3516

// async global->LDS, 16B per lane; LDS dest = wave-uniform base + lane*16
__device__ __forceinline__ void gl2lds16(const __half* g, __half* l) {
  __builtin_amdgcn_global_load_lds(
      (const __attribute__((address_space(1))) void*)g,
      (__attribute__((address_space(3))) void*)l,
      16, 0, 0);
}
__device__ __forceinline__ void gl2lds16f(const float* g, float* l) {
  __builtin_amdgcn_global_load_lds(
      (const __attribute__((address_space(1))) void*)g,
      (__attribute__((address_space(3))) void*)l,
      16, 0, 0);
}

__device__ __forceinline__ void cvt8(const float* in, __half* out, int i) {
  float4 a = *(const float4*)&in[i];
  float4 b = *(const float4*)&in[i + 4];
  half8 h;
  h[0] = (_Float16)a.x; h[1] = (_Float16)a.y; h[2] = (_Float16)a.z; h[3] = (_Float16)a.w;
  h[4] = (_Float16)b.x; h[5] = (_Float16)b.y; h[6] = (_Float16)b.z; h[7] = (_Float16)b.w;
  *(half8*)&out[i] = h;
}

// ---------------- fused prep: cvt wq/wp + mask bit-pack + bias gather ---------
__global__ __launch_bounds__(256) void prep_k(
    const float* __restrict__ wq,     __half* __restrict__ wqh,
    const float* __restrict__ wp,     __half* __restrict__ wph,
    const float* __restrict__ mask,   unsigned int* __restrict__ mbits,
    const int* __restrict__ rel_index, const float* __restrict__ table,
    __half* __restrict__ bias_sw) {
  const int blk = blockIdx.x;
  const int tid = threadIdx.x;

  if (blk < NWQB) {                                  // cvt w_qkv -> fp16
    int i = (blk * 256 + tid) * 8;
    if (i < NWQ) cvt8(wq, wqh, i);
    return;
  }
  if (blk < NWQB + NWPB) {                           // cvt w_proj -> fp16
    int i = ((blk - NWQB) * 256 + tid) * 8;
    if (i < NWP) cvt8(wp, wph, i);
    return;
  }
  if (blk < NWQB + NWPB + NMKB) {                    // mask bit-pack
    int row = (blk - NWQB - NWPB) * 4 + (tid >> 6);
    int lane = tid & 63;
    if (row >= NWIN * NTOK) return;
    const float* mr = mask + (size_t)row * NTOK;
#pragma unroll
    for (int seg = 0; seg < 6; ++seg) {
      int j = seg * 64 + lane;
      bool allowed = (j < NTOK) ? (mr[j] == 0.0f) : false;
      unsigned long long bits = __ballot(allowed);
      if (lane == 0) mbits[(size_t)row * MBW + seg*2] = (unsigned)bits;
      if (lane == 1 && seg*2 + 1 < MBW) mbits[(size_t)row * MBW + seg*2 + 1] = (unsigned)(bits >> 32);
    }
    return;
  }
  {                                                  // bias gather, fragment-order
    int t = (blk - NWQB - NWPB - NMKB) * 256 + tid;
    if (t >= BSWT) return;
    int r  = t & 3;
    int lr = (t >> 2) & 15;
    int lg = (t >> 6) & 3;
    int jt = (t >> 8) % BJT;
    int ti = (t >> 8) / BJT;
    int i = ti * 16 + lg * 4 + r;
    int j = jt * 16 + lr;
    if (i < NTOK && j < NTOK) {
      int idx = rel_index[i * NTOK + j];
#pragma unroll
      for (int hh = 0; hh < NH; ++hh)
        bias_sw[(size_t)hh * BSWT + t] = __float2half(table[idx * NH + hh]);
    } else {
      __half pad = __float2half(-1000.0f);
#pragma unroll
      for (int hh = 0; hh < NH; ++hh)
        bias_sw[(size_t)hh * BSWT + t] = pad;
    }
  }
}

// ---------------- MFMA GEMM (gl2lds staging, BK=64, XCD swizzle) --------------
// A_F32=1: A staged as fp32 (2048 16B chunks/K-step), converted to fp16 at
// fragment read (same RNE rounding as a pre-pass -> bitwise-identical MFMA
// inputs). Eliminates the separate x->fp16 conversion kernel + 67 MB traffic.
// EPI 0: packed qkv fp16 store (scale cols f<384).  EPI 1: fp32 out = acc+bias.
template<int A_F32, int EPI>
__global__ __launch_bounds__(256) void gemm_mfma_k(
    const void* __restrict__ Av, const __half* __restrict__ Bh,
    const float* __restrict__ bias, void* __restrict__ Cv) {
  __shared__ __align__(16) unsigned char AsRaw[A_F32 ? 32768 : 16384];
  __shared__ __half Bs[1024 * 8];   // [kg 8][row 128][8] = 16 KB
  float*  AsF = (float*)AsRaw;      // A_F32: [kg 16][row 128][4 floats]
  __half* AsH = (__half*)AsRaw;     // else : [kg 8][row 128][8 halves]
  const int tid  = threadIdx.x;
  const int lane = tid & 63, wave = tid >> 6;
  const int lr = lane & 15, lg = lane >> 4;
  const int wr = wave >> 1, wc = wave & 1;

  // XCD-bijective swizzle of the flat block id (m204)
  const int nwg = gridDim.x * gridDim.y;
  const int flat = blockIdx.y * gridDim.x + blockIdx.x;
  const int q = nwg >> 3, rr = nwg & 7;
  const int xcd = flat & 7, lid = flat >> 3;
  const int swz = (xcd < rr ? xcd * (q + 1) : rr * (q + 1) + (xcd - rr) * q) + lid;
  const int n0 = (swz % gridDim.x) * 128;
  const int m0 = (swz / gridDim.x) * 128;
  const int KD = 384;

  f32x4 acc[4][4];
#pragma unroll
  for (int i = 0; i < 4; ++i)
#pragma unroll
    for (int j = 0; j < 4; ++j) acc[i][j] = (f32x4){0.f, 0.f, 0.f, 0.f};

  for (int k0 = 0; k0 < KD; k0 += 64) {
    // stage A
#pragma unroll
    for (int i = 0; i < (A_F32 ? 8 : 4); ++i) {
      int cb = wave * (A_F32 ? 512 : 256) + i * 64;  // wave-uniform chunk base
      int c  = cb + lane;
      if (A_F32) {
        int row = c & 127, kg = c >> 7;              // kg 0..15 (4 floats each)
        gl2lds16f(&((const float*)Av)[(size_t)(m0 + row) * KD + k0 + kg * 4],
                  &AsF[cb * 4]);
      } else {
        int row = c & 127, kg = c >> 7;              // kg 0..7 (8 halves each)
        gl2lds16(&((const __half*)Av)[(size_t)(m0 + row) * KD + k0 + kg * 8],
                 &AsH[cb * 8]);
      }
    }
    // stage B
#pragma unroll
    for (int i = 0; i < 4; ++i) {
      int cb = wave * 256 + i * 64;
      int c  = cb + lane;
      int row = c & 127, kg = c >> 7;
      gl2lds16(&Bh[(size_t)(n0 + row) * KD + k0 + kg * 8], &Bs[cb * 8]);
    }
    __syncthreads();

#pragma unroll
    for (int kk = 0; kk < 2; ++kk) {         // two K=32 halves
      const int kg = lg + kk * 4;            // kg8 0..7
      half8 af[4], bf[4];
#pragma unroll
      for (int t = 0; t < 4; ++t) {
        int row = wr * 64 + t * 16 + lr;
        if (A_F32) {
          float4 a0 = *(const float4*)&AsF[((2 * kg)     * 128 + row) * 4];
          float4 a1 = *(const float4*)&AsF[((2 * kg + 1) * 128 + row) * 4];
          half8 h;
          h[0] = (_Float16)a0.x; h[1] = (_Float16)a0.y; h[2] = (_Float16)a0.z; h[3] = (_Float16)a0.w;
          h[4] = (_Float16)a1.x; h[5] = (_Float16)a1.y; h[6] = (_Float16)a1.z; h[7] = (_Float16)a1.w;
          af[t] = h;
        } else {
          af[t] = *(const half8*)&AsH[(kg * 128 + row) * 8];
        }
        bf[t] = *(const half8*)&Bs[(kg * 128 + wc * 64 + t * 16 + lr) * 8];
      }
#pragma unroll
      for (int mi = 0; mi < 4; ++mi)
#pragma unroll
        for (int ni = 0; ni < 4; ++ni)
          acc[mi][ni] = __builtin_amdgcn_mfma_f32_16x16x32_f16(af[mi], bf[ni], acc[mi][ni], 0, 0, 0);
    }
    __syncthreads();
  }

#pragma unroll
  for (int mi = 0; mi < 4; ++mi) {
#pragma unroll
    for (int r = 0; r < 4; ++r) {
      int m = m0 + wr * 64 + mi * 16 + lg * 4 + r;
#pragma unroll
      for (int ni = 0; ni < 4; ++ni) {
        int f = n0 + wc * 64 + ni * 16 + lr;
        float v = acc[mi][ni][r];
        if (EPI == 0) {
          if (f < CDIM) v *= 0.17677669529663687f;   // q scale
          ((__half*)Cv)[(size_t)m * QKVF + f] = __float2half(v);
        } else {
          ((float*)Cv)[(size_t)m * CDIM + f] = v + bias[f];
        }
      }
    }
  }
}

// ---------------- MFMA attention: 1 block per (b,h), 8 waves (round-14) ------
// FROZEN at the round-17 codegen optimum (VGPR=84, 156 us). Eight incremental
// rewrites (r9-r12, r15, r16, r18) all regressed via regalloc perturbation
// around s[22]. Do not touch.
__global__ __launch_bounds__(512, 1) void attn_k(
    const __half* __restrict__ qkvh, const __half* __restrict__ bias_sw,
    const unsigned int* __restrict__ mbits, __half* __restrict__ av) {
  extern __shared__ __half smem[];
  __half* Ks = smem;                 // [NPAD][KSTR]
  __half* Vt = smem + LDS_K;         // [DH][VSTR]
  const int tid  = threadIdx.x;
  const int wave = tid >> 6, lane = tid & 63;
  const int lr   = lane & 15, lg = lane >> 4;
  __half* Pw = smem + LDS_K + LDS_V + wave * LDS_P;  // per-wave [16][PSTR]

  const int bh = blockIdx.x;
  const int b  = bh / NH, h = bh - b * NH;
  const int w  = b & (NWIN - 1);
  const size_t tbase = (size_t)b * NTOK;
  const int hoff = h * DH;

  for (int idx = tid; idx < NPAD * 4; idx += 512) {
    int j = idx >> 2, off = (idx & 3) << 3;
    half8 val = {0,0,0,0,0,0,0,0};
    if (j < NTOK) val = *reinterpret_cast<const half8*>(&qkvh[(tbase + j) * QKVF + CDIM + hoff + off]);
    *reinterpret_cast<half8*>(&Ks[j * KSTR + off]) = val;
  }
  for (int idx = tid; idx < NPAD * 4; idx += 512) {
    int j = idx >> 2, off = (idx & 3) << 3;
    if (j < NTOK) {
      union { float4 f; __half h[8]; } u;
      u.f = *reinterpret_cast<const float4*>(&qkvh[(tbase + j) * QKVF + 2 * CDIM + hoff + off]);
#pragma unroll
      for (int uu = 0; uu < 8; ++uu) Vt[(off + uu) * VSTR + j] = u.h[uu];
    } else {
#pragma unroll
      for (int uu = 0; uu < 8; ++uu) Vt[(off + uu) * VSTR + j] = __float2half(0.f);
    }
  }
  __syncthreads();

  const __half* bias_h = bias_sw + (size_t)h * BSWT;
  const unsigned int* mb_w = mbits + (size_t)w * NTOK * MBW;
  const int lgofs = lg * 64 + lr * 4;       // per-lane bias offset within a jt

  for (int i0 = wave * 16; i0 < NPAD; i0 += 128) {
    int qrow = min(i0 + lr, NTOK - 1);
    half8 qa = *reinterpret_cast<const half8*>(&qkvh[(tbase + qrow) * QKVF + hoff + lg * 8]);

    // QK^T: 22 j-tiles
    f32x4 s[22];
    const f32x4 zf = {0.f, 0.f, 0.f, 0.f};
#pragma unroll
    for (int jt = 0; jt < 22; ++jt) {
      half8 kb = *reinterpret_cast<const half8*>(&Ks[(jt * 16 + lr) * KSTR + lg * 8]);
      s[jt] = __builtin_amdgcn_mfma_f32_16x16x32_f16(qa, kb, zf, 0, 0, 0);
    }

    int il[4];
#pragma unroll
    for (int r = 0; r < 4; ++r) il[r] = min(i0 + lg * 4 + r, NTOK - 1);

    // bias (coalesced half4, fragment-order layout) + mask (round-8 path).
    const __half* bias_t = bias_h + (size_t)(i0 >> 4) * (BJT * 256) + lgofs;
#pragma unroll
    for (int jt = 0; jt < 22; ++jt) {
      half4 bt = *(const half4*)&bias_t[jt * 256];
      unsigned sh = (unsigned)(((jt & 1) << 4) + lr);
#pragma unroll
      for (int r = 0; r < 4; ++r) {
        unsigned mwv = mb_w[il[r] * MBW + (jt >> 1)];
        float madd = ((mwv >> sh) & 1u) ? 0.f : -100.f;
        s[jt][r] += (float)bt[r] + madd;
      }
    }

    float mx[4] = {-1e30f, -1e30f, -1e30f, -1e30f};
#pragma unroll
    for (int jt = 0; jt < 22; ++jt)
#pragma unroll
      for (int r = 0; r < 4; ++r) mx[r] = fmaxf(mx[r], s[jt][r]);
#pragma unroll
    for (int off = 1; off <= 8; off <<= 1)
#pragma unroll
      for (int r = 0; r < 4; ++r) mx[r] = fmaxf(mx[r], __shfl_xor(mx[r], off));
    float sm[4] = {0.f, 0.f, 0.f, 0.f};
#pragma unroll
    for (int jt = 0; jt < 22; ++jt)
#pragma unroll
      for (int r = 0; r < 4; ++r) {
        float p = __expf(s[jt][r] - mx[r]);
        s[jt][r] = p;
        sm[r] += p;
      }
#pragma unroll
    for (int off = 1; off <= 8; off <<= 1)
#pragma unroll
      for (int r = 0; r < 4; ++r) sm[r] += __shfl_xor(sm[r], off);

    // chunked P->LDS + PV: 4 chunks of <=96 keys through a [16][106] buffer
    f32x4 o0 = {0.f, 0.f, 0.f, 0.f}, o1 = {0.f, 0.f, 0.f, 0.f};
#pragma unroll
    for (int c = 0; c < 4; ++c) {
      const int njt = (c < 3) ? 6 : 4;     // chunk 3 covers keys 288..351
#pragma unroll
      for (int jtl = 0; jtl < njt; ++jtl) {
        int jt = c * 6 + jtl;
#pragma unroll
        for (int r = 0; r < 4; ++r)
          Pw[(lg * 4 + r) * PSTR + jtl * 16 + lr] = __float2half(s[jt][r]);
      }
      asm volatile("s_waitcnt lgkmcnt(0)" ::: "memory");
      __builtin_amdgcn_sched_barrier(0);
      const int nkt = (c < 3) ? 3 : 2;
#pragma unroll
      for (int ktl = 0; ktl < nkt; ++ktl) {
        int ktg = c * 3 + ktl;
        half8 pa  = *reinterpret_cast<const half8*>(&Pw[lr * PSTR + ktl * 32 + lg * 8]);
        half8 vb0 = *reinterpret_cast<const half8*>(&Vt[lr * VSTR + ktg * 32 + lg * 8]);
        half8 vb1 = *reinterpret_cast<const half8*>(&Vt[(16 + lr) * VSTR + ktg * 32 + lg * 8]);
        o0 = __builtin_amdgcn_mfma_f32_16x16x32_f16(pa, vb0, o0, 0, 0, 0);
        o1 = __builtin_amdgcn_mfma_f32_16x16x32_f16(pa, vb1, o1, 0, 0, 0);
      }
    }

#pragma unroll
    for (int r = 0; r < 4; ++r) {
      int i = i0 + lg * 4 + r;
      if (i < NTOK) {
        float inv = 1.f / sm[r];
        size_t ob = ((size_t)b * NTOK + i) * CDIM + hoff;
        av[ob + lr]      = __float2half(o0[r] * inv);
        av[ob + 16 + lr] = __float2half(o1[r] * inv);
      }
    }
  }
}

extern "C" void kernel_launch(void* const* d_in, const int* in_sizes, int n_in,
                              void* d_out, int out_size, void* d_ws, size_t ws_size,
                              hipStream_t stream) {
  const float* x          = (const float*)d_in[0];
  const float* mask       = (const float*)d_in[4];
  const float* w_qkv      = (const float*)d_in[6];
  const float* bias_table = (const float*)d_in[7];
  const float* w_proj     = (const float*)d_in[8];
  const float* b_proj     = (const float*)d_in[9];
  const int*   rel_index  = (const int*)d_in[10];
  float* out = (float*)d_out;

  // ws (~139.6 MB): qkvh [MTOK][1152] fp16, avb [MTOK][384] fp16,
  // bias_sw [12][22*22*256] fp16, mbits, wqkvh, wprojh  (xh eliminated)
  __half* qkvh   = (__half*)d_ws;
  __half* avb    = qkvh + (size_t)MTOK * QKVF;
  __half* bias_sw = avb + (size_t)MTOK * CDIM;
  unsigned int* mbits = (unsigned int*)(bias_sw + (size_t)NH * BSWT);
  __half* wqkvh  = (__half*)(mbits + (size_t)NWIN * NTOK * MBW);
  __half* wprojh = wqkvh + (size_t)QKVF * CDIM;

  // fused prep: cvt wq/wp + mask pack + bias gather (x-cvt fused into GEMM)
  prep_k<<<PREPB, 256, 0, stream>>>(w_qkv, wqkvh, w_proj, wprojh,
                                    mask, mbits, rel_index, bias_table, bias_sw);

  // QKV: A = x (fp32, staged+converted in-kernel), B = wqkvh, C = packed qkvh
  gemm_mfma_k<1, 0><<<dim3(QKVF / 128, MTOK / 128), 256, 0, stream>>>(
      x, wqkvh, nullptr, qkvh);

  (void)hipFuncSetAttribute((const void*)attn_k,
                            hipFuncAttributeMaxDynamicSharedMemorySize, LDS_TOT * 2);
  attn_k<<<BATCH * NH, 512, LDS_TOT * 2, stream>>>(qkvh, bias_sw, mbits, avb);

  // proj: A = avb (fp16), B = wprojh, C = out (fp32 + bias)
  gemm_mfma_k<0, 1><<<dim3(CDIM / 128, MTOK / 128), 256, 0, stream>>>(
      avb, wprojh, b_proj, out);
}

// Round 21
// 296.963 us; speedup vs baseline: 1.1698x; 1.1698x over previous
//
#include <hip/hip_runtime.h>
#include <hip/hip_fp16.h>
#include <math.h>

#define BATCH 128
#define NTOK  343
#define NPAD  352
#define CDIM  384
#define NH    12
#define DH    32
#define NWIN  32
#define MTOK  (BATCH*NTOK)   // 43904
#define NN    (NTOK*NTOK)    // 117649
#define QKVF  (3*CDIM)       // 1152
#define KSTR  40             // attn K LDS row stride (halves)
#define VSTR  360
#define PSTR  106            // chunked P buffer stride (halves); conflict-verified
#define MBW   11             // u32 words per packed mask row
#define BTI   22             // bias_sw i-tiles
#define BJT   22             // bias_sw j-tiles
#define BSWT  (BTI*BJT*256)  // elements per head in bias_sw (123904)

typedef float    f32x4 __attribute__((ext_vector_type(4)));
typedef _Float16 half8 __attribute__((ext_vector_type(8)));
typedef _Float16 half4 __attribute__((ext_vector_type(4)));

#define LDS_K   (NPAD*KSTR)                 // 14080 halves = 28160 B
#define LDS_V   (DH*VSTR)                   // 11520 halves = 23040 B
#define LDS_P   (16*PSTR)                   // 1696 halves  = 3392 B per wave
#define LDS_TOT (LDS_K + LDS_V + 8*LDS_P)   // 39168 halves = 78336 B

// prep_k grid sections
#define NX    (MTOK*CDIM)          // 16,859,136
#define NWQ   (QKVF*CDIM)          // 442,368
#define NWP   (CDIM*CDIM)          // 147,456
#define NXB   (NX/2048)            // 8232 blocks
#define NWQB  (NWQ/2048)           // 216
#define NWPB  (NWP/2048)           // 72
#define NMKB  ((NWIN*NTOK+3)/4)    // 2744
#define NBSB  ((BSWT+255)/256)     // 484
#define PREPB (NXB+NWQB+NWPB+NMKB+NBSB)  // 11748

// async global->LDS, 16B per lane; LDS dest = wave-uniform base + lane*16
__device__ __forceinline__ void gl2lds16(const __half* g, __half* l) {
  __builtin_amdgcn_global_load_lds(
      (const __attribute__((address_space(1))) void*)g,
      (__attribute__((address_space(3))) void*)l,
      16, 0, 0);
}

__device__ __forceinline__ void cvt8(const float* in, __half* out, int i) {
  float4 a = *(const float4*)&in[i];
  float4 b = *(const float4*)&in[i + 4];
  half8 h;
  h[0] = (_Float16)a.x; h[1] = (_Float16)a.y; h[2] = (_Float16)a.z; h[3] = (_Float16)a.w;
  h[4] = (_Float16)b.x; h[5] = (_Float16)b.y; h[6] = (_Float16)b.z; h[7] = (_Float16)b.w;
  *(half8*)&out[i] = h;
}

// ---------------- fused prep: cvt x/wq/wp + mask bit-pack + bias gather -------
__global__ __launch_bounds__(256) void prep_k(
    const float* __restrict__ x,      __half* __restrict__ xh,
    const float* __restrict__ wq,     __half* __restrict__ wqh,
    const float* __restrict__ wp,     __half* __restrict__ wph,
    const float* __restrict__ mask,   unsigned int* __restrict__ mbits,
    const int* __restrict__ rel_index, const float* __restrict__ table,
    __half* __restrict__ bias_sw) {
  const int blk = blockIdx.x;
  const int tid = threadIdx.x;

  if (blk < NXB) {                                   // cvt x -> fp16
    int i = (blk * 256 + tid) * 8;
    if (i < NX) cvt8(x, xh, i);
    return;
  }
  if (blk < NXB + NWQB) {                            // cvt w_qkv -> fp16
    int i = ((blk - NXB) * 256 + tid) * 8;
    if (i < NWQ) cvt8(wq, wqh, i);
    return;
  }
  if (blk < NXB + NWQB + NWPB) {                     // cvt w_proj -> fp16
    int i = ((blk - NXB - NWQB) * 256 + tid) * 8;
    if (i < NWP) cvt8(wp, wph, i);
    return;
  }
  if (blk < NXB + NWQB + NWPB + NMKB) {              // mask bit-pack
    int row = (blk - NXB - NWQB - NWPB) * 4 + (tid >> 6);
    int lane = tid & 63;
    if (row >= NWIN * NTOK) return;
    const float* mr = mask + (size_t)row * NTOK;
#pragma unroll
    for (int seg = 0; seg < 6; ++seg) {
      int j = seg * 64 + lane;
      bool allowed = (j < NTOK) ? (mr[j] == 0.0f) : false;
      unsigned long long bits = __ballot(allowed);
      if (lane == 0) mbits[(size_t)row * MBW + seg*2] = (unsigned)bits;
      if (lane == 1 && seg*2 + 1 < MBW) mbits[(size_t)row * MBW + seg*2 + 1] = (unsigned)(bits >> 32);
    }
    return;
  }
  {                                                  // bias gather, fragment-order
    int t = (blk - NXB - NWQB - NWPB - NMKB) * 256 + tid;
    if (t >= BSWT) return;
    int r  = t & 3;
    int lr = (t >> 2) & 15;
    int lg = (t >> 6) & 3;
    int jt = (t >> 8) % BJT;
    int ti = (t >> 8) / BJT;
    int i = ti * 16 + lg * 4 + r;
    int j = jt * 16 + lr;
    if (i < NTOK && j < NTOK) {
      int idx = rel_index[i * NTOK + j];
#pragma unroll
      for (int hh = 0; hh < NH; ++hh)
        bias_sw[(size_t)hh * BSWT + t] = __float2half(table[idx * NH + hh]);
    } else {
      __half pad = __float2half(-1000.0f);
#pragma unroll
      for (int hh = 0; hh < NH; ++hh)
        bias_sw[(size_t)hh * BSWT + t] = pad;
    }
  }
}

// ---------------- MFMA GEMM (all-fp16, gl2lds staging, BK=64, XCD swizzle) ----
// EPI 0: packed qkv fp16 store (scale cols f<384).  EPI 1: fp32 out = acc+bias.
template<int EPI>
__global__ __launch_bounds__(256) void gemm_mfma_k(
    const __half* __restrict__ Ah, const __half* __restrict__ Bh,
    const float* __restrict__ bias, void* __restrict__ Cv) {
  __shared__ __half As[1024 * 8];   // [kg 8][row 128][8]  = 16 KB
  __shared__ __half Bs[1024 * 8];
  const int tid  = threadIdx.x;
  const int lane = tid & 63, wave = tid >> 6;
  const int lr = lane & 15, lg = lane >> 4;
  const int wr = wave >> 1, wc = wave & 1;

  // XCD-bijective swizzle of the flat block id (m204)
  const int nwg = gridDim.x * gridDim.y;
  const int flat = blockIdx.y * gridDim.x + blockIdx.x;
  const int q = nwg >> 3, rr = nwg & 7;
  const int xcd = flat & 7, lid = flat >> 3;
  const int swz = (xcd < rr ? xcd * (q + 1) : rr * (q + 1) + (xcd - rr) * q) + lid;
  const int n0 = (swz % gridDim.x) * 128;
  const int m0 = (swz / gridDim.x) * 128;
  const int KD = 384;

  f32x4 acc[4][4];
#pragma unroll
  for (int i = 0; i < 4; ++i)
#pragma unroll
    for (int j = 0; j < 4; ++j) acc[i][j] = (f32x4){0.f, 0.f, 0.f, 0.f};

  for (int k0 = 0; k0 < KD; k0 += 64) {
#pragma unroll
    for (int i = 0; i < 4; ++i) {
      int cb = wave * 256 + i * 64;          // wave-uniform chunk base
      int c  = cb + lane;
      int row = c & 127, kg = c >> 7;        // kg 0..7
      gl2lds16(&Ah[(size_t)(m0 + row) * KD + k0 + kg * 8], &As[cb * 8]);
      gl2lds16(&Bh[(size_t)(n0 + row) * KD + k0 + kg * 8], &Bs[cb * 8]);
    }
    __syncthreads();

#pragma unroll
    for (int kk = 0; kk < 2; ++kk) {         // two K=32 halves
      const int kg = lg + kk * 4;
      half8 af[4], bf[4];
#pragma unroll
      for (int t = 0; t < 4; ++t) {
        af[t] = *(const half8*)&As[(kg * 128 + wr * 64 + t * 16 + lr) * 8];
        bf[t] = *(const half8*)&Bs[(kg * 128 + wc * 64 + t * 16 + lr) * 8];
      }
#pragma unroll
      for (int mi = 0; mi < 4; ++mi)
#pragma unroll
        for (int ni = 0; ni < 4; ++ni)
          acc[mi][ni] = __builtin_amdgcn_mfma_f32_16x16x32_f16(af[mi], bf[ni], acc[mi][ni], 0, 0, 0);
    }
    __syncthreads();
  }

#pragma unroll
  for (int mi = 0; mi < 4; ++mi) {
#pragma unroll
    for (int r = 0; r < 4; ++r) {
      int m = m0 + wr * 64 + mi * 16 + lg * 4 + r;
#pragma unroll
      for (int ni = 0; ni < 4; ++ni) {
        int f = n0 + wc * 64 + ni * 16 + lr;
        float v = acc[mi][ni][r];
        if (EPI == 0) {
          if (f < CDIM) v *= 0.17677669529663687f;   // q scale
          ((__half*)Cv)[(size_t)m * QKVF + f] = __float2half(v);
        } else {
          ((float*)Cv)[(size_t)m * CDIM + f] = v + bias[f];
        }
      }
    }
  }
}

// ---------------- MFMA attention: 1 block per (b,h), 8 waves (round-14) ------
// FROZEN at the round-17 codegen optimum (VGPR=84, 156 us). Do not touch.
__global__ __launch_bounds__(512, 1) void attn_k(
    const __half* __restrict__ qkvh, const __half* __restrict__ bias_sw,
    const unsigned int* __restrict__ mbits, __half* __restrict__ av) {
  extern __shared__ __half smem[];
  __half* Ks = smem;                 // [NPAD][KSTR]
  __half* Vt = smem + LDS_K;         // [DH][VSTR]
  const int tid  = threadIdx.x;
  const int wave = tid >> 6, lane = tid & 63;
  const int lr   = lane & 15, lg = lane >> 4;
  __half* Pw = smem + LDS_K + LDS_V + wave * LDS_P;  // per-wave [16][PSTR]

  const int bh = blockIdx.x;
  const int b  = bh / NH, h = bh - b * NH;
  const int w  = b & (NWIN - 1);
  const size_t tbase = (size_t)b * NTOK;
  const int hoff = h * DH;

  for (int idx = tid; idx < NPAD * 4; idx += 512) {
    int j = idx >> 2, off = (idx & 3) << 3;
    half8 val = {0,0,0,0,0,0,0,0};
    if (j < NTOK) val = *reinterpret_cast<const half8*>(&qkvh[(tbase + j) * QKVF + CDIM + hoff + off]);
    *reinterpret_cast<half8*>(&Ks[j * KSTR + off]) = val;
  }
  for (int idx = tid; idx < NPAD * 4; idx += 512) {
    int j = idx >> 2, off = (idx & 3) << 3;
    if (j < NTOK) {
      union { float4 f; __half h[8]; } u;
      u.f = *reinterpret_cast<const float4*>(&qkvh[(tbase + j) * QKVF + 2 * CDIM + hoff + off]);
#pragma unroll
      for (int uu = 0; uu < 8; ++uu) Vt[(off + uu) * VSTR + j] = u.h[uu];
    } else {
#pragma unroll
      for (int uu = 0; uu < 8; ++uu) Vt[(off + uu) * VSTR + j] = __float2half(0.f);
    }
  }
  __syncthreads();

  const __half* bias_h = bias_sw + (size_t)h * BSWT;
  const unsigned int* mb_w = mbits + (size_t)w * NTOK * MBW;
  const int lgofs = lg * 64 + lr * 4;       // per-lane bias offset within a jt

  for (int i0 = wave * 16; i0 < NPAD; i0 += 128) {
    int qrow = min(i0 + lr, NTOK - 1);
    half8 qa = *reinterpret_cast<const half8*>(&qkvh[(tbase + qrow) * QKVF + hoff + lg * 8]);

    // QK^T: 22 j-tiles
    f32x4 s[22];
    const f32x4 zf = {0.f, 0.f, 0.f, 0.f};
#pragma unroll
    for (int jt = 0; jt < 22; ++jt) {
      half8 kb = *reinterpret_cast<const half8*>(&Ks[(jt * 16 + lr) * KSTR + lg * 8]);
      s[jt] = __builtin_amdgcn_mfma_f32_16x16x32_f16(qa, kb, zf, 0, 0, 0);
    }

    int il[4];
#pragma unroll
    for (int r = 0; r < 4; ++r) il[r] = min(i0 + lg * 4 + r, NTOK - 1);

    // bias (coalesced half4, fragment-order layout) + mask (round-8 path).
    const __half* bias_t = bias_h + (size_t)(i0 >> 4) * (BJT * 256) + lgofs;
#pragma unroll
    for (int jt = 0; jt < 22; ++jt) {
      half4 bt = *(const half4*)&bias_t[jt * 256];
      unsigned sh = (unsigned)(((jt & 1) << 4) + lr);
#pragma unroll
      for (int r = 0; r < 4; ++r) {
        unsigned mwv = mb_w[il[r] * MBW + (jt >> 1)];
        float madd = ((mwv >> sh) & 1u) ? 0.f : -100.f;
        s[jt][r] += (float)bt[r] + madd;
      }
    }

    float mx[4] = {-1e30f, -1e30f, -1e30f, -1e30f};
#pragma unroll
    for (int jt = 0; jt < 22; ++jt)
#pragma unroll
      for (int r = 0; r < 4; ++r) mx[r] = fmaxf(mx[r], s[jt][r]);
#pragma unroll
    for (int off = 1; off <= 8; off <<= 1)
#pragma unroll
      for (int r = 0; r < 4; ++r) mx[r] = fmaxf(mx[r], __shfl_xor(mx[r], off));
    float sm[4] = {0.f, 0.f, 0.f, 0.f};
#pragma unroll
    for (int jt = 0; jt < 22; ++jt)
#pragma unroll
      for (int r = 0; r < 4; ++r) {
        float p = __expf(s[jt][r] - mx[r]);
        s[jt][r] = p;
        sm[r] += p;
      }
#pragma unroll
    for (int off = 1; off <= 8; off <<= 1)
#pragma unroll
      for (int r = 0; r < 4; ++r) sm[r] += __shfl_xor(sm[r], off);

    // chunked P->LDS + PV: 4 chunks of <=96 keys through a [16][106] buffer
    f32x4 o0 = {0.f, 0.f, 0.f, 0.f}, o1 = {0.f, 0.f, 0.f, 0.f};
#pragma unroll
    for (int c = 0; c < 4; ++c) {
      const int njt = (c < 3) ? 6 : 4;     // chunk 3 covers keys 288..351
#pragma unroll
      for (int jtl = 0; jtl < njt; ++jtl) {
        int jt = c * 6 + jtl;
#pragma unroll
        for (int r = 0; r < 4; ++r)
          Pw[(lg * 4 + r) * PSTR + jtl * 16 + lr] = __float2half(s[jt][r]);
      }
      asm volatile("s_waitcnt lgkmcnt(0)" ::: "memory");
      __builtin_amdgcn_sched_barrier(0);
      const int nkt = (c < 3) ? 3 : 2;
#pragma unroll
      for (int ktl = 0; ktl < nkt; ++ktl) {
        int ktg = c * 3 + ktl;
        half8 pa  = *reinterpret_cast<const half8*>(&Pw[lr * PSTR + ktl * 32 + lg * 8]);
        half8 vb0 = *reinterpret_cast<const half8*>(&Vt[lr * VSTR + ktg * 32 + lg * 8]);
        half8 vb1 = *reinterpret_cast<const half8*>(&Vt[(16 + lr) * VSTR + ktg * 32 + lg * 8]);
        o0 = __builtin_amdgcn_mfma_f32_16x16x32_f16(pa, vb0, o0, 0, 0, 0);
        o1 = __builtin_amdgcn_mfma_f32_16x16x32_f16(pa, vb1, o1, 0, 0, 0);
      }
    }

#pragma unroll
    for (int r = 0; r < 4; ++r) {
      int i = i0 + lg * 4 + r;
      if (i < NTOK) {
        float inv = 1.f / sm[r];
        size_t ob = ((size_t)b * NTOK + i) * CDIM + hoff;
        av[ob + lr]      = __float2half(o0[r] * inv);
        av[ob + 16 + lr] = __float2half(o1[r] * inv);
      }
    }
  }
}

extern "C" void kernel_launch(void* const* d_in, const int* in_sizes, int n_in,
                              void* d_out, int out_size, void* d_ws, size_t ws_size,
                              hipStream_t stream) {
  const float* x          = (const float*)d_in[0];
  const float* mask       = (const float*)d_in[4];
  const float* w_qkv      = (const float*)d_in[6];
  const float* bias_table = (const float*)d_in[7];
  const float* w_proj     = (const float*)d_in[8];
  const float* b_proj     = (const float*)d_in[9];
  const int*   rel_index  = (const int*)d_in[10];
  float* out = (float*)d_out;

  // ws (~139.6 MB): qkvh [MTOK][1152] fp16, avb [MTOK][384] fp16 (alias xh),
  // bias_sw [12][22*22*256] fp16, mbits, wqkvh, wprojh
  __half* qkvh   = (__half*)d_ws;
  __half* avb    = qkvh + (size_t)MTOK * QKVF;
  __half* xh     = avb;                                  // alias
  __half* bias_sw = avb + (size_t)MTOK * CDIM;
  unsigned int* mbits = (unsigned int*)(bias_sw + (size_t)NH * BSWT);
  __half* wqkvh  = (__half*)(mbits + (size_t)NWIN * NTOK * MBW);
  __half* wprojh = wqkvh + (size_t)QKVF * CDIM;

  // fused prep: cvt x/wq/wp + mask pack + bias gather in ONE launch
  prep_k<<<PREPB, 256, 0, stream>>>(x, xh, w_qkv, wqkvh, w_proj, wprojh,
                                    mask, mbits, rel_index, bias_table, bias_sw);

  // QKV: A = xh, B = wqkvh, C = packed qkvh (fp16, q scaled)
  gemm_mfma_k<0><<<dim3(QKVF / 128, MTOK / 128), 256, 0, stream>>>(
      xh, wqkvh, nullptr, qkvh);

  (void)hipFuncSetAttribute((const void*)attn_k,
                            hipFuncAttributeMaxDynamicSharedMemorySize, LDS_TOT * 2);
  attn_k<<<BATCH * NH, 512, LDS_TOT * 2, stream>>>(qkvh, bias_sw, mbits, avb);

  // proj: A = avb (fp16), B = wprojh, C = out (fp32 + bias)
  gemm_mfma_k<1><<<dim3(CDIM / 128, MTOK / 128), 256, 0, stream>>>(
      avb, wprojh, b_proj, out);
}

// Round 22
// 268.763 us; speedup vs baseline: 1.2925x; 1.1049x over previous
//
#include <hip/hip_runtime.h>
#include <hip/hip_fp16.h>
#include <math.h>

#define BATCH 128
#define NTOK  343
#define NPAD  352
#define CDIM  384
#define NH    12
#define DH    32
#define NWIN  32
#define MTOK  (BATCH*NTOK)   // 43904
#define NN    (NTOK*NTOK)    // 117649
#define QKVF  (3*CDIM)       // 1152
#define KSTR  40             // attn K LDS row stride (halves)
#define VSTR  360
#define PSTR  106            // chunked P buffer stride (halves); conflict-verified
#define MBW   11             // u32 words per packed mask row
#define BTI   22             // bias_sw i-tiles
#define BJT   22             // bias_sw j-tiles
#define BSWT  (BTI*BJT*256)  // elements per head in bias_sw (123904)

#define LOG2E 1.4426950408889634f

typedef float    f32x4 __attribute__((ext_vector_type(4)));
typedef _Float16 half8 __attribute__((ext_vector_type(8)));
typedef _Float16 half4 __attribute__((ext_vector_type(4)));

#define LDS_K   (NPAD*KSTR)                 // 14080 halves = 28160 B
#define LDS_V   (DH*VSTR)                   // 11520 halves = 23040 B
#define LDS_P   (16*PSTR)                   // 1696 halves  = 3392 B per wave
#define LDS_TOT (LDS_K + LDS_V + 8*LDS_P)   // 39168 halves = 78336 B

// prep_k grid sections
#define NX    (MTOK*CDIM)          // 16,859,136
#define NWQ   (QKVF*CDIM)          // 442,368
#define NWP   (CDIM*CDIM)          // 147,456
#define NXB   (NX/2048)            // 8232 blocks
#define NWQB  (NWQ/2048)           // 216
#define NWPB  (NWP/2048)           // 72
#define NMKB  ((NWIN*NTOK+3)/4)    // 2744
#define NBSB  ((BSWT+255)/256)     // 484
#define PREPB (NXB+NWQB+NWPB+NMKB+NBSB)  // 11748

// async global->LDS, 16B per lane; LDS dest = wave-uniform base + lane*16
__device__ __forceinline__ void gl2lds16(const __half* g, __half* l) {
  __builtin_amdgcn_global_load_lds(
      (const __attribute__((address_space(1))) void*)g,
      (__attribute__((address_space(3))) void*)l,
      16, 0, 0);
}

__device__ __forceinline__ void cvt8(const float* in, __half* out, int i) {
  float4 a = *(const float4*)&in[i];
  float4 b = *(const float4*)&in[i + 4];
  half8 h;
  h[0] = (_Float16)a.x; h[1] = (_Float16)a.y; h[2] = (_Float16)a.z; h[3] = (_Float16)a.w;
  h[4] = (_Float16)b.x; h[5] = (_Float16)b.y; h[6] = (_Float16)b.z; h[7] = (_Float16)b.w;
  *(half8*)&out[i] = h;
}

// ---------------- fused prep: cvt x/wq/wp + mask bit-pack + bias gather -------
// bias pre-scaled by LOG2E (scores live in log2 units); pad -1000 -> exp2 = 0.
__global__ __launch_bounds__(256) void prep_k(
    const float* __restrict__ x,      __half* __restrict__ xh,
    const float* __restrict__ wq,     __half* __restrict__ wqh,
    const float* __restrict__ wp,     __half* __restrict__ wph,
    const float* __restrict__ mask,   unsigned int* __restrict__ mbits,
    const int* __restrict__ rel_index, const float* __restrict__ table,
    __half* __restrict__ bias_sw) {
  const int blk = blockIdx.x;
  const int tid = threadIdx.x;

  if (blk < NXB) {                                   // cvt x -> fp16
    int i = (blk * 256 + tid) * 8;
    if (i < NX) cvt8(x, xh, i);
    return;
  }
  if (blk < NXB + NWQB) {                            // cvt w_qkv -> fp16
    int i = ((blk - NXB) * 256 + tid) * 8;
    if (i < NWQ) cvt8(wq, wqh, i);
    return;
  }
  if (blk < NXB + NWQB + NWPB) {                     // cvt w_proj -> fp16
    int i = ((blk - NXB - NWQB) * 256 + tid) * 8;
    if (i < NWP) cvt8(wp, wph, i);
    return;
  }
  if (blk < NXB + NWQB + NWPB + NMKB) {              // mask bit-pack
    int row = (blk - NXB - NWQB - NWPB) * 4 + (tid >> 6);
    int lane = tid & 63;
    if (row >= NWIN * NTOK) return;
    const float* mr = mask + (size_t)row * NTOK;
#pragma unroll
    for (int seg = 0; seg < 6; ++seg) {
      int j = seg * 64 + lane;
      bool allowed = (j < NTOK) ? (mr[j] == 0.0f) : false;
      unsigned long long bits = __ballot(allowed);
      if (lane == 0) mbits[(size_t)row * MBW + seg*2] = (unsigned)bits;
      if (lane == 1 && seg*2 + 1 < MBW) mbits[(size_t)row * MBW + seg*2 + 1] = (unsigned)(bits >> 32);
    }
    return;
  }
  {                                                  // bias gather, fragment-order
    int t = (blk - NXB - NWQB - NWPB - NMKB) * 256 + tid;
    if (t >= BSWT) return;
    int r  = t & 3;
    int lr = (t >> 2) & 15;
    int lg = (t >> 6) & 3;
    int jt = (t >> 8) % BJT;
    int ti = (t >> 8) / BJT;
    int i = ti * 16 + lg * 4 + r;
    int j = jt * 16 + lr;
    if (i < NTOK && j < NTOK) {
      int idx = rel_index[i * NTOK + j];
#pragma unroll
      for (int hh = 0; hh < NH; ++hh)
        bias_sw[(size_t)hh * BSWT + t] = __float2half(table[idx * NH + hh] * LOG2E);
    } else {
      __half pad = __float2half(-1000.0f);
#pragma unroll
      for (int hh = 0; hh < NH; ++hh)
        bias_sw[(size_t)hh * BSWT + t] = pad;
    }
  }
}

// ---------------- MFMA GEMM (all-fp16, gl2lds staging, BK=64, XCD swizzle) ----
// EPI 0: packed qkv fp16 store (q scaled by 32^-0.5 * LOG2E -> log2 units).
// EPI 1: fp32 out = acc + bias.
template<int EPI>
__global__ __launch_bounds__(256) void gemm_mfma_k(
    const __half* __restrict__ Ah, const __half* __restrict__ Bh,
    const float* __restrict__ bias, void* __restrict__ Cv) {
  __shared__ __half As[1024 * 8];   // [kg 8][row 128][8]  = 16 KB
  __shared__ __half Bs[1024 * 8];
  const int tid  = threadIdx.x;
  const int lane = tid & 63, wave = tid >> 6;
  const int lr = lane & 15, lg = lane >> 4;
  const int wr = wave >> 1, wc = wave & 1;

  // XCD-bijective swizzle of the flat block id (m204)
  const int nwg = gridDim.x * gridDim.y;
  const int flat = blockIdx.y * gridDim.x + blockIdx.x;
  const int q = nwg >> 3, rr = nwg & 7;
  const int xcd = flat & 7, lid = flat >> 3;
  const int swz = (xcd < rr ? xcd * (q + 1) : rr * (q + 1) + (xcd - rr) * q) + lid;
  const int n0 = (swz % gridDim.x) * 128;
  const int m0 = (swz / gridDim.x) * 128;
  const int KD = 384;

  f32x4 acc[4][4];
#pragma unroll
  for (int i = 0; i < 4; ++i)
#pragma unroll
    for (int j = 0; j < 4; ++j) acc[i][j] = (f32x4){0.f, 0.f, 0.f, 0.f};

  for (int k0 = 0; k0 < KD; k0 += 64) {
#pragma unroll
    for (int i = 0; i < 4; ++i) {
      int cb = wave * 256 + i * 64;          // wave-uniform chunk base
      int c  = cb + lane;
      int row = c & 127, kg = c >> 7;        // kg 0..7
      gl2lds16(&Ah[(size_t)(m0 + row) * KD + k0 + kg * 8], &As[cb * 8]);
      gl2lds16(&Bh[(size_t)(n0 + row) * KD + k0 + kg * 8], &Bs[cb * 8]);
    }
    __syncthreads();

#pragma unroll
    for (int kk = 0; kk < 2; ++kk) {         // two K=32 halves
      const int kg = lg + kk * 4;
      half8 af[4], bf[4];
#pragma unroll
      for (int t = 0; t < 4; ++t) {
        af[t] = *(const half8*)&As[(kg * 128 + wr * 64 + t * 16 + lr) * 8];
        bf[t] = *(const half8*)&Bs[(kg * 128 + wc * 64 + t * 16 + lr) * 8];
      }
#pragma unroll
      for (int mi = 0; mi < 4; ++mi)
#pragma unroll
        for (int ni = 0; ni < 4; ++ni)
          acc[mi][ni] = __builtin_amdgcn_mfma_f32_16x16x32_f16(af[mi], bf[ni], acc[mi][ni], 0, 0, 0);
    }
    __syncthreads();
  }

#pragma unroll
  for (int mi = 0; mi < 4; ++mi) {
#pragma unroll
    for (int r = 0; r < 4; ++r) {
      int m = m0 + wr * 64 + mi * 16 + lg * 4 + r;
#pragma unroll
      for (int ni = 0; ni < 4; ++ni) {
        int f = n0 + wc * 64 + ni * 16 + lr;
        float v = acc[mi][ni][r];
        if (EPI == 0) {
          if (f < CDIM) v *= (0.17677669529663687f * LOG2E);   // q scale, log2 units
          ((__half*)Cv)[(size_t)m * QKVF + f] = __float2half(v);
        } else {
          ((float*)Cv)[(size_t)m * CDIM + f] = v + bias[f];
        }
      }
    }
  }
}

// ---------------- MFMA attention: 1 block per (b,h), 8 waves ----------------
// r12-chunked (s[6] live state -> ~2 blocks/CU) + r15/16-validated fixed-max
// exp2 softmax (scores in log2 units, bounded; no max pass, no rescale).
// Mask stays additive (-100*LOG2E); padding bias=-1000 -> exp2 underflows to 0.
__global__ __launch_bounds__(512, 1) void attn_k(
    const __half* __restrict__ qkvh, const __half* __restrict__ bias_sw,
    const unsigned int* __restrict__ mbits, __half* __restrict__ av) {
  extern __shared__ __half smem[];
  __half* Ks = smem;                 // [NPAD][KSTR]
  __half* Vt = smem + LDS_K;         // [DH][VSTR]
  const int tid  = threadIdx.x;
  const int wave = tid >> 6, lane = tid & 63;
  const int lr   = lane & 15, lg = lane >> 4;
  __half* Pw = smem + LDS_K + LDS_V + wave * LDS_P;  // per-wave [16][PSTR]

  const int bh = blockIdx.x;
  const int b  = bh / NH, h = bh - b * NH;
  const int w  = b & (NWIN - 1);
  const size_t tbase = (size_t)b * NTOK;
  const int hoff = h * DH;

  for (int idx = tid; idx < NPAD * 4; idx += 512) {
    int j = idx >> 2, off = (idx & 3) << 3;
    half8 val = {0,0,0,0,0,0,0,0};
    if (j < NTOK) val = *reinterpret_cast<const half8*>(&qkvh[(tbase + j) * QKVF + CDIM + hoff + off]);
    *reinterpret_cast<half8*>(&Ks[j * KSTR + off]) = val;
  }
  for (int idx = tid; idx < NPAD * 4; idx += 512) {
    int j = idx >> 2, off = (idx & 3) << 3;
    if (j < NTOK) {
      union { float4 f; __half h[8]; } u;
      u.f = *reinterpret_cast<const float4*>(&qkvh[(tbase + j) * QKVF + 2 * CDIM + hoff + off]);
#pragma unroll
      for (int uu = 0; uu < 8; ++uu) Vt[(off + uu) * VSTR + j] = u.h[uu];
    } else {
#pragma unroll
      for (int uu = 0; uu < 8; ++uu) Vt[(off + uu) * VSTR + j] = __float2half(0.f);
    }
  }
  __syncthreads();

  const __half* bias_h = bias_sw + (size_t)h * BSWT;
  const unsigned int* mb_w = mbits + (size_t)w * NTOK * MBW;
  const int lgofs = lg * 64 + lr * 4;       // per-lane bias offset within a jt

  for (int i0 = wave * 16; i0 < NPAD; i0 += 128) {
    int qrow = min(i0 + lr, NTOK - 1);
    half8 qa = *reinterpret_cast<const half8*>(&qkvh[(tbase + qrow) * QKVF + hoff + lg * 8]);

    int il[4];
#pragma unroll
    for (int r = 0; r < 4; ++r) il[r] = min(i0 + lg * 4 + r, NTOK - 1);
    const __half* bias_t = bias_h + (size_t)(i0 >> 4) * (BJT * 256) + lgofs;

    f32x4 o0 = {0.f, 0.f, 0.f, 0.f}, o1 = {0.f, 0.f, 0.f, 0.f};
    float sm[4] = {0.f, 0.f, 0.f, 0.f};
    const f32x4 zf = {0.f, 0.f, 0.f, 0.f};

#pragma unroll
    for (int c = 0; c < 4; ++c) {
      const int njt = (c < 3) ? 6 : 4;   // chunk 3 covers keys 288..351
      const int nkt = (c < 3) ? 3 : 2;

      // QK^T for this chunk (C = 0); q pre-scaled to log2 units
      f32x4 s[6];
#pragma unroll
      for (int jl_ = 0; jl_ < njt; ++jl_) {
        int jt = c * 6 + jl_;
        half8 kb = *reinterpret_cast<const half8*>(&Ks[(jt * 16 + lr) * KSTR + lg * 8]);
        s[jl_] = __builtin_amdgcn_mfma_f32_16x16x32_f16(qa, kb, zf, 0, 0, 0);
      }

      // fused bias + mask + fixed-max exp2 + partial-sum + P-store (one pass)
#pragma unroll
      for (int jl_ = 0; jl_ < njt; ++jl_) {
        int jt = c * 6 + jl_;
        half4 bt = *(const half4*)&bias_t[jt * 256];
        unsigned sh = (unsigned)(((jt & 1) << 4) + lr);
#pragma unroll
        for (int r = 0; r < 4; ++r) {
          unsigned mwv = mb_w[il[r] * MBW + (jt >> 1)];
          float madd = ((mwv >> sh) & 1u) ? 0.f : (-100.f * LOG2E);
          float p = exp2f(s[jl_][r] + (float)bt[r] + madd);
          sm[r] += p;
          Pw[(lg * 4 + r) * PSTR + jl_ * 16 + lr] = __float2half(p);
        }
      }
      asm volatile("s_waitcnt lgkmcnt(0)" ::: "memory");
      __builtin_amdgcn_sched_barrier(0);

      // PV for this chunk
#pragma unroll
      for (int ktl = 0; ktl < nkt; ++ktl) {
        int ktg = c * 3 + ktl;
        half8 pa  = *reinterpret_cast<const half8*>(&Pw[lr * PSTR + ktl * 32 + lg * 8]);
        half8 vb0 = *reinterpret_cast<const half8*>(&Vt[lr * VSTR + ktg * 32 + lg * 8]);
        half8 vb1 = *reinterpret_cast<const half8*>(&Vt[(16 + lr) * VSTR + ktg * 32 + lg * 8]);
        o0 = __builtin_amdgcn_mfma_f32_16x16x32_f16(pa, vb0, o0, 0, 0, 0);
        o1 = __builtin_amdgcn_mfma_f32_16x16x32_f16(pa, vb1, o1, 0, 0, 0);
      }
      __builtin_amdgcn_sched_barrier(0);   // keep chunk liveness separate
    }

    // final sum butterfly (per-lane partials, no rescale needed)
#pragma unroll
    for (int off = 1; off <= 8; off <<= 1)
#pragma unroll
      for (int r = 0; r < 4; ++r) sm[r] += __shfl_xor(sm[r], off);

#pragma unroll
    for (int r = 0; r < 4; ++r) {
      int i = i0 + lg * 4 + r;
      if (i < NTOK) {
        float inv = 1.f / sm[r];
        size_t ob = ((size_t)b * NTOK + i) * CDIM + hoff;
        av[ob + lr]      = __float2half(o0[r] * inv);
        av[ob + 16 + lr] = __float2half(o1[r] * inv);
      }
    }
  }
}

extern "C" void kernel_launch(void* const* d_in, const int* in_sizes, int n_in,
                              void* d_out, int out_size, void* d_ws, size_t ws_size,
                              hipStream_t stream) {
  const float* x          = (const float*)d_in[0];
  const float* mask       = (const float*)d_in[4];
  const float* w_qkv      = (const float*)d_in[6];
  const float* bias_table = (const float*)d_in[7];
  const float* w_proj     = (const float*)d_in[8];
  const float* b_proj     = (const float*)d_in[9];
  const int*   rel_index  = (const int*)d_in[10];
  float* out = (float*)d_out;

  // ws (~139.6 MB): qkvh [MTOK][1152] fp16, avb [MTOK][384] fp16 (alias xh),
  // bias_sw [12][22*22*256] fp16, mbits, wqkvh, wprojh
  __half* qkvh   = (__half*)d_ws;
  __half* avb    = qkvh + (size_t)MTOK * QKVF;
  __half* xh     = avb;                                  // alias
  __half* bias_sw = avb + (size_t)MTOK * CDIM;
  unsigned int* mbits = (unsigned int*)(bias_sw + (size_t)NH * BSWT);
  __half* wqkvh  = (__half*)(mbits + (size_t)NWIN * NTOK * MBW);
  __half* wprojh = wqkvh + (size_t)QKVF * CDIM;

  // fused prep: cvt x/wq/wp + mask pack + bias gather in ONE launch
  prep_k<<<PREPB, 256, 0, stream>>>(x, xh, w_qkv, wqkvh, w_proj, wprojh,
                                    mask, mbits, rel_index, bias_table, bias_sw);

  // QKV: A = xh, B = wqkvh, C = packed qkvh (fp16, q scaled to log2 units)
  gemm_mfma_k<0><<<dim3(QKVF / 128, MTOK / 128), 256, 0, stream>>>(
      xh, wqkvh, nullptr, qkvh);

  (void)hipFuncSetAttribute((const void*)attn_k,
                            hipFuncAttributeMaxDynamicSharedMemorySize, LDS_TOT * 2);
  attn_k<<<BATCH * NH, 512, LDS_TOT * 2, stream>>>(qkvh, bias_sw, mbits, avb);

  // proj: A = avb (fp16), B = wprojh, C = out (fp32 + bias)
  gemm_mfma_k<1><<<dim3(CDIM / 128, MTOK / 128), 256, 0, stream>>>(
      avb, wprojh, b_proj, out);
}

// Round 25
// 260.996 us; speedup vs baseline: 1.3310x; 1.0298x over previous
//
#include <hip/hip_runtime.h>
#include <hip/hip_fp16.h>
#include <math.h>

#define BATCH 128
#define NTOK  343
#define NPAD  352
#define CDIM  384
#define NH    12
#define DH    32
#define NWIN  32
#define MTOK  (BATCH*NTOK)   // 43904
#define NN    (NTOK*NTOK)    // 117649
#define QKVF  (3*CDIM)       // 1152
#define KSTR  40             // attn K LDS row stride (halves)
#define VSTR  360
#define PSTR  108            // P stride: 54 dwords; b64-aligned; 2-way bank (free)
#define MBW   11             // u32 words per packed mask row
#define BTI   22             // bias_sw i-tiles
#define BJT   22             // bias_sw j-tiles
#define BSWT  (BTI*BJT*256)  // elements per head in bias_sw (123904)

#define LOG2E 1.4426950408889634f

typedef float    f32x4 __attribute__((ext_vector_type(4)));
typedef _Float16 half8 __attribute__((ext_vector_type(8)));
typedef _Float16 half4 __attribute__((ext_vector_type(4)));

#define LDS_K   (NPAD*KSTR)                 // 14080 halves = 28160 B
#define LDS_V   (DH*VSTR)                   // 11520 halves = 23040 B
#define LDS_P   (16*PSTR)                   // 1728 halves  = 3456 B per wave
#define LDS_TOT (LDS_K + LDS_V + 8*LDS_P)   // 39424 halves = 78848 B (2 blocks/CU)

// prep_k grid sections
#define NX    (MTOK*CDIM)          // 16,859,136
#define NWQ   (QKVF*CDIM)          // 442,368
#define NWP   (CDIM*CDIM)          // 147,456
#define NXB   (NX/2048)            // 8232 blocks
#define NWQB  (NWQ/2048)           // 216
#define NWPB  (NWP/2048)           // 72
#define NMKB  ((NWIN*NTOK+3)/4)    // 2744
#define NBSB  ((BSWT+255)/256)     // 484
#define PREPB (NXB+NWQB+NWPB+NMKB+NBSB)  // 11748

// async global->LDS, 16B per lane; LDS dest = wave-uniform base + lane*16
__device__ __forceinline__ void gl2lds16(const __half* g, __half* l) {
  __builtin_amdgcn_global_load_lds(
      (const __attribute__((address_space(1))) void*)g,
      (__attribute__((address_space(3))) void*)l,
      16, 0, 0);
}

__device__ __forceinline__ void cvt8(const float* in, __half* out, int i) {
  float4 a = *(const float4*)&in[i];
  float4 b = *(const float4*)&in[i + 4];
  half8 h;
  h[0] = (_Float16)a.x; h[1] = (_Float16)a.y; h[2] = (_Float16)a.z; h[3] = (_Float16)a.w;
  h[4] = (_Float16)b.x; h[5] = (_Float16)b.y; h[6] = (_Float16)b.z; h[7] = (_Float16)b.w;
  *(half8*)&out[i] = h;
}

// ---------------- fused prep: cvt x/wq/wp + mask bit-pack + bias gather -------
// bias fragment order for SWAPPED QK layout: value at index
// t=(((ti*22+jt)*4+lg)*16+lr)*4+r  is  bias[h][i=ti*16+lr][j=jt*16+lg*4+r]*LOG2E
// pad -1000 -> exp2 underflows to exact 0.
__global__ __launch_bounds__(256) void prep_k(
    const float* __restrict__ x,      __half* __restrict__ xh,
    const float* __restrict__ wq,     __half* __restrict__ wqh,
    const float* __restrict__ wp,     __half* __restrict__ wph,
    const float* __restrict__ mask,   unsigned int* __restrict__ mbits,
    const int* __restrict__ rel_index, const float* __restrict__ table,
    __half* __restrict__ bias_sw) {
  const int blk = blockIdx.x;
  const int tid = threadIdx.x;

  if (blk < NXB) {                                   // cvt x -> fp16
    int i = (blk * 256 + tid) * 8;
    if (i < NX) cvt8(x, xh, i);
    return;
  }
  if (blk < NXB + NWQB) {                            // cvt w_qkv -> fp16
    int i = ((blk - NXB) * 256 + tid) * 8;
    if (i < NWQ) cvt8(wq, wqh, i);
    return;
  }
  if (blk < NXB + NWQB + NWPB) {                     // cvt w_proj -> fp16
    int i = ((blk - NXB - NWQB) * 256 + tid) * 8;
    if (i < NWP) cvt8(wp, wph, i);
    return;
  }
  if (blk < NXB + NWQB + NWPB + NMKB) {              // mask bit-pack
    int row = (blk - NXB - NWQB - NWPB) * 4 + (tid >> 6);
    int lane = tid & 63;
    if (row >= NWIN * NTOK) return;
    const float* mr = mask + (size_t)row * NTOK;
#pragma unroll
    for (int seg = 0; seg < 6; ++seg) {
      int j = seg * 64 + lane;
      bool allowed = (j < NTOK) ? (mr[j] == 0.0f) : false;
      unsigned long long bits = __ballot(allowed);
      if (lane == 0) mbits[(size_t)row * MBW + seg*2] = (unsigned)bits;
      if (lane == 1 && seg*2 + 1 < MBW) mbits[(size_t)row * MBW + seg*2 + 1] = (unsigned)(bits >> 32);
    }
    return;
  }
  {                                                  // bias gather (swapped order)
    int t = (blk - NXB - NWQB - NWPB - NMKB) * 256 + tid;
    if (t >= BSWT) return;
    int r  = t & 3;
    int lr = (t >> 2) & 15;
    int lg = (t >> 6) & 3;
    int jt = (t >> 8) % BJT;
    int ti = (t >> 8) / BJT;
    int i = ti * 16 + lr;              // query from lr (swapped)
    int j = jt * 16 + lg * 4 + r;      // key from lg,r (swapped)
    if (i < NTOK && j < NTOK) {
      int idx = rel_index[i * NTOK + j];
#pragma unroll
      for (int hh = 0; hh < NH; ++hh)
        bias_sw[(size_t)hh * BSWT + t] = __float2half(table[idx * NH + hh] * LOG2E);
    } else {
      __half pad = __float2half(-1000.0f);
#pragma unroll
      for (int hh = 0; hh < NH; ++hh)
        bias_sw[(size_t)hh * BSWT + t] = pad;
    }
  }
}

// ---------------- MFMA GEMM (all-fp16, gl2lds staging, BK=64, XCD swizzle) ----
// EPI 0: packed qkv fp16 store (q scaled by 32^-0.5 * LOG2E -> log2 units).
// EPI 1: fp32 out = acc + bias.
template<int EPI>
__global__ __launch_bounds__(256) void gemm_mfma_k(
    const __half* __restrict__ Ah, const __half* __restrict__ Bh,
    const float* __restrict__ bias, void* __restrict__ Cv) {
  __shared__ __half As[1024 * 8];   // [kg 8][row 128][8]  = 16 KB
  __shared__ __half Bs[1024 * 8];
  const int tid  = threadIdx.x;
  const int lane = tid & 63, wave = tid >> 6;
  const int lr = lane & 15, lg = lane >> 4;
  const int wr = wave >> 1, wc = wave & 1;

  // XCD-bijective swizzle of the flat block id (m204)
  const int nwg = gridDim.x * gridDim.y;
  const int flat = blockIdx.y * gridDim.x + blockIdx.x;
  const int q = nwg >> 3, rr = nwg & 7;
  const int xcd = flat & 7, lid = flat >> 3;
  const int swz = (xcd < rr ? xcd * (q + 1) : rr * (q + 1) + (xcd - rr) * q) + lid;
  const int n0 = (swz % gridDim.x) * 128;
  const int m0 = (swz / gridDim.x) * 128;
  const int KD = 384;

  f32x4 acc[4][4];
#pragma unroll
  for (int i = 0; i < 4; ++i)
#pragma unroll
    for (int j = 0; j < 4; ++j) acc[i][j] = (f32x4){0.f, 0.f, 0.f, 0.f};

  for (int k0 = 0; k0 < KD; k0 += 64) {
#pragma unroll
    for (int i = 0; i < 4; ++i) {
      int cb = wave * 256 + i * 64;          // wave-uniform chunk base
      int c  = cb + lane;
      int row = c & 127, kg = c >> 7;        // kg 0..7
      gl2lds16(&Ah[(size_t)(m0 + row) * KD + k0 + kg * 8], &As[cb * 8]);
      gl2lds16(&Bh[(size_t)(n0 + row) * KD + k0 + kg * 8], &Bs[cb * 8]);
    }
    __syncthreads();

#pragma unroll
    for (int kk = 0; kk < 2; ++kk) {         // two K=32 halves
      const int kg = lg + kk * 4;
      half8 af[4], bf[4];
#pragma unroll
      for (int t = 0; t < 4; ++t) {
        af[t] = *(const half8*)&As[(kg * 128 + wr * 64 + t * 16 + lr) * 8];
        bf[t] = *(const half8*)&Bs[(kg * 128 + wc * 64 + t * 16 + lr) * 8];
      }
#pragma unroll
      for (int mi = 0; mi < 4; ++mi)
#pragma unroll
        for (int ni = 0; ni < 4; ++ni)
          acc[mi][ni] = __builtin_amdgcn_mfma_f32_16x16x32_f16(af[mi], bf[ni], acc[mi][ni], 0, 0, 0);
    }
    __syncthreads();
  }

#pragma unroll
  for (int mi = 0; mi < 4; ++mi) {
#pragma unroll
    for (int r = 0; r < 4; ++r) {
      int m = m0 + wr * 64 + mi * 16 + lg * 4 + r;
#pragma unroll
      for (int ni = 0; ni < 4; ++ni) {
        int f = n0 + wc * 64 + ni * 16 + lr;
        float v = acc[mi][ni][r];
        if (EPI == 0) {
          if (f < CDIM) v *= (0.17677669529663687f * LOG2E);   // q scale, log2 units
          ((__half*)Cv)[(size_t)m * QKVF + f] = __float2half(v);
        } else {
          ((float*)Cv)[(size_t)m * CDIM + f] = v + bias[f];
        }
      }
    }
  }
}

// ---------------- MFMA attention: 1 block per (b,h), 8 waves ----------------
// r22 chunked fixed-max base + SWAPPED QK operands: mfma(K,Q) -> lane holds
// S[key=jt*16+lg*4+r][query=i0+lr]. P-store: one b64 per jt at CHUNK-LOCAL
// key offset jl_*16+lg*4 (r24 bug: used global jt -> buffer overflow).
__global__ __launch_bounds__(512, 1) void attn_k(
    const __half* __restrict__ qkvh, const __half* __restrict__ bias_sw,
    const unsigned int* __restrict__ mbits, __half* __restrict__ av) {
  extern __shared__ __half smem[];
  __half* Ks = smem;                 // [NPAD][KSTR]
  __half* Vt = smem + LDS_K;         // [DH][VSTR]
  const int tid  = threadIdx.x;
  const int wave = tid >> 6, lane = tid & 63;
  const int lr   = lane & 15, lg = lane >> 4;
  __half* Pw = smem + LDS_K + LDS_V + wave * LDS_P;  // per-wave [16][PSTR]

  const int bh = blockIdx.x;
  const int b  = bh / NH, h = bh - b * NH;
  const int w  = b & (NWIN - 1);
  const size_t tbase = (size_t)b * NTOK;
  const int hoff = h * DH;

  for (int idx = tid; idx < NPAD * 4; idx += 512) {
    int j = idx >> 2, off = (idx & 3) << 3;
    half8 val = {0,0,0,0,0,0,0,0};
    if (j < NTOK) val = *reinterpret_cast<const half8*>(&qkvh[(tbase + j) * QKVF + CDIM + hoff + off]);
    *reinterpret_cast<half8*>(&Ks[j * KSTR + off]) = val;
  }
  for (int idx = tid; idx < NPAD * 4; idx += 512) {
    int j = idx >> 2, off = (idx & 3) << 3;
    if (j < NTOK) {
      union { float4 f; __half h[8]; } u;
      u.f = *reinterpret_cast<const float4*>(&qkvh[(tbase + j) * QKVF + 2 * CDIM + hoff + off]);
#pragma unroll
      for (int uu = 0; uu < 8; ++uu) Vt[(off + uu) * VSTR + j] = u.h[uu];
    } else {
#pragma unroll
      for (int uu = 0; uu < 8; ++uu) Vt[(off + uu) * VSTR + j] = __float2half(0.f);
    }
  }
  __syncthreads();

  const __half* bias_h = bias_sw + (size_t)h * BSWT;
  const unsigned int* mb_w = mbits + (size_t)w * NTOK * MBW;
  const int lgofs = lg * 64 + lr * 4;       // per-lane bias offset within a jt

  for (int i0 = wave * 16; i0 < NPAD; i0 += 128) {
    int qrow = min(i0 + lr, NTOK - 1);
    half8 qa = *reinterpret_cast<const half8*>(&qkvh[(tbase + qrow) * QKVF + hoff + lg * 8]);

    const int il = min(i0 + lr, NTOK - 1);            // this lane's query row
    const unsigned int* mb_i = mb_w + il * MBW;       // its mask-bit row (over keys)
    const __half* bias_t = bias_h + (size_t)(i0 >> 4) * (BJT * 256) + lgofs;

    f32x4 o0 = {0.f, 0.f, 0.f, 0.f}, o1 = {0.f, 0.f, 0.f, 0.f};
    float sm = 0.f;                                   // partial over this lane's keys
    const f32x4 zf = {0.f, 0.f, 0.f, 0.f};

#pragma unroll
    for (int c = 0; c < 4; ++c) {
      const int njt = (c < 3) ? 6 : 4;   // chunk 3 covers keys 288..351
      const int nkt = (c < 3) ? 3 : 2;

      // QK^T swapped: s[jl][r] = S[key=jt*16+lg*4+r][query=i0+lr]
      f32x4 s[6];
#pragma unroll
      for (int jl_ = 0; jl_ < njt; ++jl_) {
        int jt = c * 6 + jl_;
        half8 kb = *reinterpret_cast<const half8*>(&Ks[(jt * 16 + lr) * KSTR + lg * 8]);
        s[jl_] = __builtin_amdgcn_mfma_f32_16x16x32_f16(kb, qa, zf, 0, 0, 0);
      }

      // fused bias + mask + fixed-max exp2 + partial-sum + packed b64 P-store
#pragma unroll
      for (int jl_ = 0; jl_ < njt; ++jl_) {
        int jt = c * 6 + jl_;
        half4 bt = *(const half4*)&bias_t[jt * 256];
        unsigned mwv = mb_i[jt >> 1];                 // word over keys (one per jt)
        unsigned sh = (unsigned)(((jt & 1) << 4) + lg * 4);
        float p[4];
#pragma unroll
        for (int r = 0; r < 4; ++r) {
          float madd = ((mwv >> (sh + r)) & 1u) ? 0.f : (-100.f * LOG2E);
          p[r] = exp2f(s[jl_][r] + (float)bt[r] + madd);
          sm += p[r];
        }
        half4 hv;
        hv[0] = (_Float16)p[0]; hv[1] = (_Float16)p[1];
        hv[2] = (_Float16)p[2]; hv[3] = (_Float16)p[3];
        // CHUNK-LOCAL key offset (jl_), matching the PV read below
        *(half4*)&Pw[lr * PSTR + jl_ * 16 + lg * 4] = hv;
      }
      asm volatile("s_waitcnt lgkmcnt(0)" ::: "memory");
      __builtin_amdgcn_sched_barrier(0);

      // PV for this chunk (P layout [query][chunk-local key])
#pragma unroll
      for (int ktl = 0; ktl < nkt; ++ktl) {
        int ktg = c * 3 + ktl;
        half8 pa  = *reinterpret_cast<const half8*>(&Pw[lr * PSTR + ktl * 32 + lg * 8]);
        half8 vb0 = *reinterpret_cast<const half8*>(&Vt[lr * VSTR + ktg * 32 + lg * 8]);
        half8 vb1 = *reinterpret_cast<const half8*>(&Vt[(16 + lr) * VSTR + ktg * 32 + lg * 8]);
        o0 = __builtin_amdgcn_mfma_f32_16x16x32_f16(pa, vb0, o0, 0, 0, 0);
        o1 = __builtin_amdgcn_mfma_f32_16x16x32_f16(pa, vb1, o1, 0, 0, 0);
      }
      __builtin_amdgcn_sched_barrier(0);   // keep chunk liveness separate
    }

    // row sum lives at query=i0+lr, sliced across lg: reduce over lg bits
    sm += __shfl_xor(sm, 16);
    sm += __shfl_xor(sm, 32);

    // redistribute: output row r needs sum of query i0+lg*4+r (lane lr'=lg*4+r)
#pragma unroll
    for (int r = 0; r < 4; ++r) {
      int i = i0 + lg * 4 + r;
      if (i < NTOK) {
        float smr = __shfl(sm, (lane & 48) | (lg * 4 + r));
        float inv = 1.f / smr;
        size_t ob = ((size_t)b * NTOK + i) * CDIM + hoff;
        av[ob + lr]      = __float2half(o0[r] * inv);
        av[ob + 16 + lr] = __float2half(o1[r] * inv);
      }
    }
  }
}

extern "C" void kernel_launch(void* const* d_in, const int* in_sizes, int n_in,
                              void* d_out, int out_size, void* d_ws, size_t ws_size,
                              hipStream_t stream) {
  const float* x          = (const float*)d_in[0];
  const float* mask       = (const float*)d_in[4];
  const float* w_qkv      = (const float*)d_in[6];
  const float* bias_table = (const float*)d_in[7];
  const float* w_proj     = (const float*)d_in[8];
  const float* b_proj     = (const float*)d_in[9];
  const int*   rel_index  = (const int*)d_in[10];
  float* out = (float*)d_out;

  // ws (~139.6 MB): qkvh [MTOK][1152] fp16, avb [MTOK][384] fp16 (alias xh),
  // bias_sw [12][22*22*256] fp16, mbits, wqkvh, wprojh
  __half* qkvh   = (__half*)d_ws;
  __half* avb    = qkvh + (size_t)MTOK * QKVF;
  __half* xh     = avb;                                  // alias
  __half* bias_sw = avb + (size_t)MTOK * CDIM;
  unsigned int* mbits = (unsigned int*)(bias_sw + (size_t)NH * BSWT);
  __half* wqkvh  = (__half*)(mbits + (size_t)NWIN * NTOK * MBW);
  __half* wprojh = wqkvh + (size_t)QKVF * CDIM;

  // fused prep: cvt x/wq/wp + mask pack + bias gather in ONE launch
  prep_k<<<PREPB, 256, 0, stream>>>(x, xh, w_qkv, wqkvh, w_proj, wprojh,
                                    mask, mbits, rel_index, bias_table, bias_sw);

  // QKV: A = xh, B = wqkvh, C = packed qkvh (fp16, q scaled to log2 units)
  gemm_mfma_k<0><<<dim3(QKVF / 128, MTOK / 128), 256, 0, stream>>>(
      xh, wqkvh, nullptr, qkvh);

  (void)hipFuncSetAttribute((const void*)attn_k,
                            hipFuncAttributeMaxDynamicSharedMemorySize, LDS_TOT * 2);
  attn_k<<<BATCH * NH, 512, LDS_TOT * 2, stream>>>(qkvh, bias_sw, mbits, avb);

  // proj: A = avb (fp16), B = wprojh, C = out (fp32 + bias)
  gemm_mfma_k<1><<<dim3(CDIM / 128, MTOK / 128), 256, 0, stream>>>(
      avb, wprojh, b_proj, out);
}